// Round 8
// baseline (136.806 us; speedup 1.0000x reference)
//
#include <hip/hip_runtime.h>

// GNNEncoder fused MFMA kernel (round 10: r2 pipeline at 4 blocks/CU).
// B=16, S=2048, N=64, HD=32.
// Round-9 post-mortem: barrier-free direct-load loop LOST to r2's
// staged+barrier loop (72 vs 60 us) — the cooperative xs staging is a
// prefetch pipeline that amortizes x-load latency for all 4 waves; the
// barrier-free version exposes per-wave L2 latency with only 2 waves/SIMD
// to hide it. Keep the pipeline; raise the wave count instead:
//  - SCHUNK 64->32: 1024 blocks (4 available/CU).
//  - LDS squeezed to exactly 40,960 B so 4 blocks fit the 160 KiB pool:
//    catg(CATP=36: 36,864) UNION red(8,192) + xs double-buffer (4,096).
//  - xs double-buffered with T14 issue-early/write-late: next tile's
//    global loads issue at the top of the iteration, ds_writes land after
//    compute; ONE barrier per iteration (r2 had two).
//  - launch_bounds(256,2) — the proven-safe bound (>=3 spills: r3/r7/r8).
//    VGPR ~108 <= 128 -> HW packs 4 waves/SIMD anyway.
//  - TCH=8 kept (2 s-rows/wave/iter, 4 independent MFMA chains/phase).
//  - per-lane adj rowsums + shfl_xor(32) (validated r7-r9): no rs LDS.
#define BN 16
#define SN 2048
#define NV 64
#define HD 32
#define TCH 8               // s-rows per iteration (2 per wave)
#define SCHUNK 32           // s per block (1024 blocks)
#define NSUB (SCHUNK / TCH) // 4
#define CATP 36             // padded f-dim of catg (72 B rows, 0-conflict r9)

typedef short  bf8_t  __attribute__((ext_vector_type(8)));   // raw-bit MFMA view
typedef __bf16 bfv8   __attribute__((ext_vector_type(8)));
typedef __bf16 bfv4   __attribute__((ext_vector_type(4)));
typedef float  f32x16 __attribute__((ext_vector_type(16)));

#define MFMA32(a, b, c) __builtin_amdgcn_mfma_f32_32x32x16_bf16( \
    __builtin_bit_cast(bf8_t, (a)), __builtin_bit_cast(bf8_t, (b)), (c), 0, 0, 0)

__global__ __launch_bounds__(256, 2) void gnn_mfma(
    const float* __restrict__ x,    // [B,S,N]
    const float* __restrict__ adj,  // [N,N]
    const float* __restrict__ w1,   // [HD]
    const float* __restrict__ b1,   // [HD]
    const float* __restrict__ w2,   // [HD, 2*HD]
    const float* __restrict__ b2,   // [HD]
    float* __restrict__ out)        // [B, N*HD]
{
    // catg (loop) and red (epilogue) never live simultaneously.
    __shared__ union SMem {
        __bf16 catg[TCH][NV][CATP];   // 36,864 B
        float  red[NV * HD];          //  8,192 B
    } sm;
    __shared__ float xs[2][TCH][NV];  //  4,096 B  -> total 40,960 B

    const int tid  = threadIdx.x;
    const int w    = tid >> 6;
    const int lane = tid & 63;
    const int l31  = lane & 31;
    const int lh   = lane >> 5;             // 0/1 half-wave
    const int b    = blockIdx.x >> 6;       // 64 chunks per batch row
    const int chk  = blockIdx.x & 63;
    const int sbase = chk * SCHUNK;

    // ---- prologue: stage tile 0 into xs[0] (coalesced, 128 threads) ----
    if (tid < 128) {
        ((float4*)&xs[0][0][0])[tid] =
            ((const float4*)(x + ((size_t)b * SN + sbase) * (size_t)NV))[tid];
    }

    // --- An B-fragments (GEMM1): per-lane row-sums from the same loads ---
    // B[k=j][n=i]: lane -> n = nt*32+l31, k = kk*16 + lh*8 + e
    bfv8 an[2][4];
    #pragma unroll
    for (int nt = 0; nt < 2; ++nt) {
        const int i = nt * 32 + l31;
        float av[4][8];
        float psum = 0.f;
        #pragma unroll
        for (int kk = 0; kk < 4; ++kk) {
            const int j0 = kk * 16 + lh * 8;
            const float4 a0 = *(const float4*)(adj + i * NV + j0);
            const float4 a1 = *(const float4*)(adj + i * NV + j0 + 4);
            av[kk][0] = a0.x; av[kk][1] = a0.y; av[kk][2] = a0.z; av[kk][3] = a0.w;
            av[kk][4] = a1.x; av[kk][5] = a1.y; av[kk][6] = a1.z; av[kk][7] = a1.w;
            psum += a0.x + a0.y + a0.z + a0.w + a1.x + a1.y + a1.z + a1.w;
        }
        const float fullsum = psum + __shfl_xor(psum, 32);  // partner half-row
        const float rsi = 1.f / (fullsum + 1e-8f);
        #pragma unroll
        for (int kk = 0; kk < 4; ++kk) {
            bfv8 v;
            #pragma unroll
            for (int e = 0; e < 8; ++e) v[e] = (__bf16)(av[kk][e] * rsi);
            an[nt][kk] = v;
        }
    }

    // --- W2^T B-fragments (GEMM2): B[k][n=f']: f' = l31, k = kk*16+lh*8+e ---
    bfv8 wf[4];
    #pragma unroll
    for (int kk = 0; kk < 4; ++kk) {
        const int k0 = kk * 16 + lh * 8;
        const float4 a0 = *(const float4*)(w2 + l31 * (2 * HD) + k0);
        const float4 a1 = *(const float4*)(w2 + l31 * (2 * HD) + k0 + 4);
        bfv8 v;
        v[0] = (__bf16)a0.x; v[1] = (__bf16)a0.y; v[2] = (__bf16)a0.z; v[3] = (__bf16)a0.w;
        v[4] = (__bf16)a1.x; v[5] = (__bf16)a1.y; v[6] = (__bf16)a1.z; v[7] = (__bf16)a1.w;
        wf[kk] = v;
    }

    // per-lane fc1/fc2 constants
    const float w1f = w1[l31];
    const float b1f = b1[l31];
    const float b2f = b2[l31];
    float w1k[2][8], b1k[2][8];
    #pragma unroll
    for (int kk = 0; kk < 2; ++kk) {
        const int k0 = kk * 16 + lh * 8;
        #pragma unroll
        for (int e = 0; e < 8; ++e) { w1k[kk][e] = w1[k0 + e]; b1k[kk][e] = b1[k0 + e]; }
    }

    f32x16 macc0, macc1;   // mean accumulators, ihalf = 0 / 1
    #pragma unroll
    for (int r = 0; r < 16; ++r) { macc0[r] = 0.f; macc1[r] = 0.f; }

    __syncthreads();   // xs[0] staged

    for (int t = 0; t < NSUB; ++t) {
        const int cur = t & 1;

        // ---- T14 issue-early: next tile's global loads into registers ----
        const bool do_stage = (t + 1 < NSUB) && (tid < 128);
        float4 stg;
        if (do_stage) {
            stg = ((const float4*)(x +
                ((size_t)b * SN + sbase + (t + 1) * TCH) * (size_t)NV))[tid];
        }

        // phase-2 scalars from LDS, issued early to hide under phase 1
        const int sl0 = 2 * w, sl1 = 2 * w + 1;
        const float xv00 = xs[cur][sl0][l31];
        const float xv01 = xs[cur][sl0][32 + l31];
        const float xv10 = xs[cur][sl1][l31];
        const float xv11 = xs[cur][sl1][32 + l31];

        // ---- Phase 1: GEMM1 -> aggT, written to catg (wave-private slices) ----
        #pragma unroll
        for (int sp = 0; sp < 2; ++sp) {
            const int sl = 2 * w + sp;
            bfv8 a1f[4];
            #pragma unroll
            for (int kk = 0; kk < 4; ++kk) {
                const int j0 = kk * 16 + lh * 8;
                const float4 xa = *(const float4*)&xs[cur][sl][j0];
                const float4 xb = *(const float4*)&xs[cur][sl][j0 + 4];
                bfv8 v;
                v[0] = (__bf16)fmaxf(xa.x * w1f + b1f, 0.f);
                v[1] = (__bf16)fmaxf(xa.y * w1f + b1f, 0.f);
                v[2] = (__bf16)fmaxf(xa.z * w1f + b1f, 0.f);
                v[3] = (__bf16)fmaxf(xa.w * w1f + b1f, 0.f);
                v[4] = (__bf16)fmaxf(xb.x * w1f + b1f, 0.f);
                v[5] = (__bf16)fmaxf(xb.y * w1f + b1f, 0.f);
                v[6] = (__bf16)fmaxf(xb.z * w1f + b1f, 0.f);
                v[7] = (__bf16)fmaxf(xb.w * w1f + b1f, 0.f);
                a1f[kk] = v;
            }
            #pragma unroll
            for (int nt = 0; nt < 2; ++nt) {
                f32x16 c;
                #pragma unroll
                for (int r = 0; r < 16; ++r) c[r] = 0.f;
                #pragma unroll
                for (int kk = 0; kk < 4; ++kk) c = MFMA32(a1f[kk], an[nt][kk], c);
                // C[m=f][n=i]: col=l31 -> i, row=(reg&3)+8*(reg>>2)+4*lh -> f
                const int i = nt * 32 + l31;
                #pragma unroll
                for (int g = 0; g < 4; ++g) {
                    const int f0 = g * 8 + 4 * lh;
                    bfv4 pv;
                    pv[0] = (__bf16)c[g * 4 + 0]; pv[1] = (__bf16)c[g * 4 + 1];
                    pv[2] = (__bf16)c[g * 4 + 2]; pv[3] = (__bf16)c[g * 4 + 3];
                    *(bfv4*)&sm.catg[sl][i][f0] = pv;
                }
            }
        }

        // ---- Phase 2: GEMM2 (same-wave catg slices) ----
        #pragma unroll
        for (int p = 0; p < 4; ++p) {
            const int sp = p >> 1;
            const int sl = 2 * w + sp;
            const int ih = p & 1;
            const int i  = ih * 32 + l31;
            const float xv = sp ? (ih ? xv11 : xv10) : (ih ? xv01 : xv00);
            f32x16 c;
            #pragma unroll
            for (int r = 0; r < 16; ++r) c[r] = 0.f;
            #pragma unroll
            for (int kk = 0; kk < 2; ++kk) {   // h part, k in [0,32)
                bfv8 v;
                #pragma unroll
                for (int e = 0; e < 8; ++e)
                    v[e] = (__bf16)fmaxf(xv * w1k[kk][e] + b1k[kk][e], 0.f);
                c = MFMA32(v, wf[kk], c);
            }
            #pragma unroll
            for (int kk = 2; kk < 4; ++kk) {   // agg part, k in [32,64)
                const int f0 = (kk - 2) * 16 + lh * 8;
                const bfv4 lo = *(const bfv4*)&sm.catg[sl][i][f0];
                const bfv4 hi = *(const bfv4*)&sm.catg[sl][i][f0 + 4];
                bfv8 v;
                #pragma unroll
                for (int e = 0; e < 4; ++e) { v[e] = lo[e]; v[e + 4] = hi[e]; }
                c = MFMA32(v, wf[kk], c);
            }
            #pragma unroll
            for (int r = 0; r < 16; ++r) {
                const float h2 = fmaxf(c[r] + b2f, 0.f);
                if (ih == 0) macc0[r] += h2; else macc1[r] += h2;
            }
        }

        // ---- T14 write-late: next tile lands in the other buffer ----
        if (do_stage) {
            ((float4*)&xs[cur ^ 1][0][0])[tid] = stg;
        }
        __syncthreads();   // stores visible; this iter's xs reads complete
    }

    // ---- epilogue: cross-wave reduce in LDS (red aliases catg), atomics ----
    // loop-end barrier already ordered all catg reads before this point
    #pragma unroll
    for (int q = 0; q < (NV * HD) / 256; ++q) sm.red[tid + q * 256] = 0.f;
    __syncthreads();   // zeroing visible to all waves
    #pragma unroll
    for (int r = 0; r < 16; ++r) {
        const int row = (r & 3) + 8 * (r >> 2) + 4 * lh;  // i within half
        atomicAdd(&sm.red[row * HD + l31], macc0[r]);
        atomicAdd(&sm.red[(row + 32) * HD + l31], macc1[r]);
    }
    __syncthreads();
    const float inv = 1.f / (float)SN;
    #pragma unroll
    for (int q = 0; q < (NV * HD) / 256; ++q) {
        const int e = tid + q * 256;       // e = i*HD + f
        atomicAdd(out + (size_t)b * (NV * HD) + e, sm.red[e] * inv);
    }
}

extern "C" void kernel_launch(void* const* d_in, const int* in_sizes, int n_in,
                              void* d_out, int out_size, void* d_ws, size_t ws_size,
                              hipStream_t stream) {
    const float* x   = (const float*)d_in[0];
    const float* adj = (const float*)d_in[1];
    const float* w1  = (const float*)d_in[2];
    const float* b1  = (const float*)d_in[3];
    const float* w2  = (const float*)d_in[4];
    const float* b2  = (const float*)d_in[5];
    float* out = (float*)d_out;

    hipMemsetAsync(out, 0, (size_t)out_size * sizeof(float), stream);
    gnn_mfma<<<dim3(BN * 64), dim3(256), 0, stream>>>(x, adj, w1, b1, w2, b2, out);
}